// Round 2
// baseline (197.327 us; speedup 1.0000x reference)
//
#include <hip/hip_runtime.h>
#include <hip/hip_bf16.h>
#include <stdint.h>

// AutoregressiveDense: B=8192, D=1024, STRIDE=16, OUT=64, L=64
#define BROWS 8192
#define DDIM  1024
#define LDIM  64
#define ODIM  64
#define NDIM  4096
#define KSTRIDE 16

typedef __attribute__((ext_vector_type(8))) short bf16x8;           // MFMA A/B frag
typedef __attribute__((ext_vector_type(4))) float f32x4;            // MFMA C/D frag
typedef __attribute__((ext_vector_type(8))) unsigned short u16x8;   // 16B bf16 store

static __device__ __forceinline__ unsigned short f2bf(float f) {
    union { float f; uint32_t u; } v; v.f = f;
    uint32_t r = 0x7FFFu + ((v.u >> 16) & 1u);
    return (unsigned short)((v.u + r) >> 16);
}

static __device__ __forceinline__ void async16(const void* g, void* l) {
    __builtin_amdgcn_global_load_lds(
        (const __attribute__((address_space(1))) void*)g,
        (__attribute__((address_space(3))) void*)l, 16, 0, 0);
}

// ---------- merged prep: blocks [0,1024) build masked W' (B^T bf16), blocks [1024,5120) convert x ----------
__global__ __launch_bounds__(256) void prep_kernel(const float* __restrict__ x,
                                                   const float* __restrict__ W,
                                                   unsigned short* __restrict__ xb,
                                                   unsigned short* __restrict__ wbt) {
    const int bid = blockIdx.x;
    if (bid < 1024) {
        // W [L][D][O] f32 -> masked bf16 W' [N=l*64+o][K=d], zero for d >= l*16
        __shared__ float tile[64][65];
        const int l  = bid >> 4;
        const int d0 = (bid & 15) << 6;
        const int t  = threadIdx.x;
        {
            const int dd = t >> 2;
            const int o4 = (t & 3) << 4;
            const float* src = W + ((size_t)((l << 10) + d0 + dd) << 6) + o4;
            #pragma unroll
            for (int j = 0; j < 4; ++j) {
                float4 v = reinterpret_cast<const float4*>(src)[j];
                tile[dd][o4 + 4 * j + 0] = v.x;
                tile[dd][o4 + 4 * j + 1] = v.y;
                tile[dd][o4 + 4 * j + 2] = v.z;
                tile[dd][o4 + 4 * j + 3] = v.w;
            }
        }
        __syncthreads();
        {
            const int o    = t >> 2;
            const int dloc = (t & 3) << 4;
            const int kmax = l * KSTRIDE;
            unsigned short* dst = wbt + ((size_t)((l << 6) + o) << 10) + d0 + dloc;
            u16x8 r0, r1;
            #pragma unroll
            for (int j = 0; j < 8; ++j) {
                int da = d0 + dloc + j;
                int db = da + 8;
                r0[j] = (da < kmax) ? f2bf(tile[dloc + j][o])     : (unsigned short)0;
                r1[j] = (db < kmax) ? f2bf(tile[dloc + 8 + j][o]) : (unsigned short)0;
            }
            *reinterpret_cast<u16x8*>(dst)     = r0;
            *reinterpret_cast<u16x8*>(dst + 8) = r1;
        }
    } else {
        int i = (bid - 1024) * 256 + threadIdx.x;
        const float4* xf = reinterpret_cast<const float4*>(x);
        float4 v0 = xf[2 * i];
        float4 v1 = xf[2 * i + 1];
        u16x8 r;
        r[0] = f2bf(v0.x); r[1] = f2bf(v0.y); r[2] = f2bf(v0.z); r[3] = f2bf(v0.w);
        r[4] = f2bf(v1.x); r[5] = f2bf(v1.y); r[6] = f2bf(v1.z); r[7] = f2bf(v1.w);
        reinterpret_cast<u16x8*>(xb)[i] = r;
    }
}

// ---------- main GEMM: 256x256 tile, BK=64, 8 waves (2Mx4N), 8-phase counted-vmcnt schedule ----------
// A = xb [8192][1024] bf16; B^T = wbt [4096][1024] bf16. nkt = bn+1 K-tiles of 64.
// LDS 128KB: buffer par in {0,1}: A at par*65536 (256 rows x 128B, XOR-swizzled), B at par*65536+32768.
// Swizzle: byte ^= ((row&7)<<4); staged via inverse-swizzled GLOBAL source + linear gload_lds dest.
#define MMQ(I0, J0, B) \
    _Pragma("unroll") \
    for (int ii = 0; ii < 4; ++ii) \
    _Pragma("unroll") \
    for (int jj = 0; jj < 2; ++jj) \
    _Pragma("unroll") \
    for (int kk = 0; kk < 2; ++kk) \
        acc[(I0) + ii][(J0) + jj] = __builtin_amdgcn_mfma_f32_16x16x32_bf16( \
            a[ii][kk], B[jj][kk], acc[(I0) + ii][(J0) + jj], 0, 0, 0);

#define BAR_MID() do { __builtin_amdgcn_s_barrier(); \
    asm volatile("s_waitcnt lgkmcnt(0)" ::: "memory"); \
    __builtin_amdgcn_sched_barrier(0); } while (0)
#define BAR_END() do { __builtin_amdgcn_sched_barrier(0); \
    __builtin_amdgcn_s_barrier(); } while (0)
#define VMW4() asm volatile("s_waitcnt vmcnt(4)" ::: "memory")

__global__ __launch_bounds__(512, 2) void ar_gemm_kernel(
        const unsigned short* __restrict__ xb,
        const unsigned short* __restrict__ wbt,
        const float* __restrict__ bias,
        float* __restrict__ out) {
    __shared__ int4 smem[8192];   // 128 KiB
    char* ldsc = (char*)smem;

    const int tid  = threadIdx.x;
    const int lane = tid & 63;
    const int wid  = tid >> 6;
    const int wm   = wid >> 2;          // 2 M-waves x 4 N-waves; wave tile 128x64
    const int wn   = wid & 3;
    const int bid  = blockIdx.x;
    const int bm   = bid & 31;
    const int bn   = 15 - (bid >> 5);   // heavy K-loops dispatch first
    const int nkt  = bn + 1;            // K-tiles of 64 (covers (4bn+3)*16)

    // staging constants: thread t stages LDS-linear o=t*16 (+8192); global granule inverse-swizzled
    const int gcol = (((tid & 7) ^ ((tid >> 3) & 7)) << 4);
    const int srow = tid >> 3;

    // ds_read swizzled granule bytes for kk=0,1: granule=(kk<<2)|(lane>>4), XOR row&7 (= lane&7)
    const int g0 = (((lane >> 4)     ^ (lane & 7)) << 4);
    const int g1 = (((4 | (lane >> 4)) ^ (lane & 7)) << 4);
    const int aoff = (wm * 128 + (lane & 15)) * 128;
    const int boff = 32768 + (wn * 64 + (lane & 15)) * 128;

    f32x4 acc[8][4];
    #pragma unroll
    for (int i = 0; i < 8; ++i)
        #pragma unroll
        for (int j = 0; j < 4; ++j)
            acc[i][j] = (f32x4)(0.f);

    bf16x8 a[4][2], bL[2][2], bH[2][2];

    // part: 0=A-half0, 1=A-half1, 2=B-half0, 3=B-half1. Out-of-range t -> clamp SOURCE only
    // (dest region is free by the schedule; data unused). Keeps vmcnt counts uniform.
    auto stage = [&](int t, int part) {
        const int ts = t < nkt ? t : nkt - 1;
        char* l = ldsc + ((t & 1) << 16) + ((part >> 1) << 15) + ((part & 1) << 14) + tid * 16;
        const unsigned short* srcm = (part >= 2) ? wbt : xb;
        const int rb = (((part >= 2) ? bn : bm) << 8) + ((part & 1) << 7) + srow;
        const char* g = (const char*)srcm + ((size_t)rb << 11) + ts * 128 + gcol;
        async16(g, l);
        async16(g + (64 << 11), l + 8192);
    };
    auto readA = [&](int par, int ih) {
        const char* p = ldsc + (par << 16) + aoff + (ih << 13);
        #pragma unroll
        for (int ii = 0; ii < 4; ++ii) {
            a[ii][0] = *(const bf16x8*)(p + ii * 2048 + g0);
            a[ii][1] = *(const bf16x8*)(p + ii * 2048 + g1);
        }
    };
    auto readB = [&](int par, int jh, bf16x8 (&b)[2][2]) {
        const char* p = ldsc + (par << 16) + boff + (jh << 12);
        #pragma unroll
        for (int jj = 0; jj < 2; ++jj) {
            b[jj][0] = *(const bf16x8*)(p + jj * 2048 + g0);
            b[jj][1] = *(const bf16x8*)(p + jj * 2048 + g1);
        }
    };

    // prologue: tile0 fully + B halves of tile1 (matches steady-state rotation entry)
    stage(0, 0); stage(0, 1); stage(0, 2); stage(0, 3);
    stage(1, 2); stage(1, 3);
    VMW4();                       // drain tile0's 8 loads; B(1) stays in flight
    __builtin_amdgcn_s_barrier();

    const int niter = (nkt + 1) >> 1;
    for (int J = 0; J < niter; ++J) {
        const int T2 = 2 * J;
        // P1: quadrant (i0-3, j0-1) of tile T2 (buffer0)
        readA(0, 0); readB(0, 0, bL);
        stage(T2 + 1, 0);
        BAR_MID();
        __builtin_amdgcn_s_setprio(1); MMQ(0, 0, bL); __builtin_amdgcn_s_setprio(0);
        BAR_END();
        // P2: (i0-3, j2-3)
        readB(0, 1, bH);
        stage(T2 + 1, 1);
        BAR_MID();
        __builtin_amdgcn_s_setprio(1); MMQ(0, 2, bH); __builtin_amdgcn_s_setprio(0);
        BAR_END();
        // P3: (i4-7, j2-3)
        readA(0, 1);
        stage(T2 + 2, 2);
        BAR_MID();
        __builtin_amdgcn_s_setprio(1); MMQ(4, 2, bH); __builtin_amdgcn_s_setprio(0);
        BAR_END();
        // P4: (i4-7, j0-1); counted vmcnt guards tile T2+1 for P5
        stage(T2 + 2, 3);
        VMW4();
        BAR_MID();
        __builtin_amdgcn_s_setprio(1); MMQ(4, 0, bL); __builtin_amdgcn_s_setprio(0);
        BAR_END();
        if (T2 + 1 >= nkt) break;   // odd-nkt tail: tile nkt-1 done in P1-P4
        // P5: tile T2+1 (buffer1), (i0-3, j0-1)
        readA(1, 0); readB(1, 0, bL);
        stage(T2 + 2, 0);
        BAR_MID();
        __builtin_amdgcn_s_setprio(1); MMQ(0, 0, bL); __builtin_amdgcn_s_setprio(0);
        BAR_END();
        // P6: (i0-3, j2-3)
        readB(1, 1, bH);
        stage(T2 + 2, 1);
        BAR_MID();
        __builtin_amdgcn_s_setprio(1); MMQ(0, 2, bH); __builtin_amdgcn_s_setprio(0);
        BAR_END();
        // P7: (i4-7, j2-3)
        readA(1, 1);
        stage(T2 + 3, 2);
        BAR_MID();
        __builtin_amdgcn_s_setprio(1); MMQ(4, 2, bH); __builtin_amdgcn_s_setprio(0);
        BAR_END();
        // P8: (i4-7, j0-1); counted vmcnt guards tiles T2+2/T2+3 for next iter
        stage(T2 + 3, 3);
        VMW4();
        BAR_MID();
        __builtin_amdgcn_s_setprio(1); MMQ(4, 0, bL); __builtin_amdgcn_s_setprio(0);
        BAR_END();
    }

    // epilogue: C/D layout col=lane&15, row=(lane>>4)*4+q; bias[col] add in f32
    const int crow0 = (bm << 8) + (wm << 7) + ((lane >> 4) << 2);
    const int ccol  = (bn << 8) + (wn << 6) + (lane & 15);
    float bv[4];
    #pragma unroll
    for (int j = 0; j < 4; ++j) bv[j] = bias[ccol + j * 16];
    #pragma unroll
    for (int i = 0; i < 8; ++i)
        #pragma unroll
        for (int j = 0; j < 4; ++j)
            #pragma unroll
            for (int q = 0; q < 4; ++q)
                out[(size_t)(crow0 + i * 16 + q) * NDIM + ccol + j * 16] = acc[i][j][q] + bv[j];
}

// ---------- fallback: naive f32 (used only if workspace too small) ----------
__global__ __launch_bounds__(256) void naive_kernel(const float* __restrict__ x,
                                                    const float* __restrict__ W,
                                                    const float* __restrict__ bias,
                                                    float* __restrict__ out) {
    size_t idx = (size_t)blockIdx.x * 256 + threadIdx.x;
    if (idx >= (size_t)BROWS * NDIM) return;
    int m = (int)(idx >> 12);
    int n = (int)(idx & 4095);
    int l = n >> 6;
    int o = n & 63;
    int kmax = l * KSTRIDE;
    float s = bias[n];
    const float* xr = x + (size_t)m * DDIM;
    const float* wp = W + ((size_t)l << 16) + o;
    for (int d = 0; d < kmax; ++d) s += xr[d] * wp[(size_t)d << 6];
    out[idx] = s;
}

extern "C" void kernel_launch(void* const* d_in, const int* in_sizes, int n_in,
                              void* d_out, int out_size, void* d_ws, size_t ws_size,
                              hipStream_t stream) {
    const float* x = (const float*)d_in[0];
    const float* W = (const float*)d_in[1];
    const float* b = (const float*)d_in[2];
    float* out = (float*)d_out;

    const size_t need = ((size_t)BROWS * DDIM + (size_t)NDIM * DDIM) * sizeof(unsigned short);
    if (ws_size < need) {
        int total = BROWS * NDIM;
        naive_kernel<<<(total + 255) / 256, 256, 0, stream>>>(x, W, b, out);
        return;
    }
    unsigned short* xbuf = (unsigned short*)d_ws;             // bf16 x  [8192][1024]
    unsigned short* wbt  = xbuf + (size_t)BROWS * DDIM;       // bf16 W' [4096][1024]

    prep_kernel<<<5120, 256, 0, stream>>>(x, W, xbuf, wbt);
    ar_gemm_kernel<<<512, 512, 0, stream>>>(xbuf, wbt, b, out);
}